// Round 6
// baseline (313.956 us; speedup 1.0000x reference)
//
#include <hip/hip_runtime.h>
#include <cstdint>

#define NROWS 16384
#define FDIM 64
#define HDIM 128
#define ODIM 512
#define KDIM 8192
#define NSTEPS 64   // k-steps per block (split-K x2: 64 * 64 = 4096)

#define BM 256
#define BN 128
#define BK 64

typedef short bf16x8 __attribute__((ext_vector_type(8)));
typedef float f32x16 __attribute__((ext_vector_type(16)));
typedef float f32x4v __attribute__((ext_vector_type(4)));
typedef uint32_t u32x4 __attribute__((ext_vector_type(4)));

__device__ __forceinline__ uint16_t rne_bf16(float f) {
  uint32_t u = __builtin_bit_cast(uint32_t, f);
  u += 0x7fffu + ((u >> 16) & 1u);
  return (uint16_t)(u >> 16);
}

// ---- pre-kernel 1: W2 [K=8192][O=512] f32 -> W2F fragment-linear bf16 ----
// Entry e (16B = one lane's 8 k-elems of one 32x32x16 B-fragment):
//   lane=e&63, nt=(e>>6)&1, wn2=(e>>7)&1, kc=(e>>8)&3, kstep=(e>>10)&127, oh=(e>>17)&3
//   col = oh*128 + wn2*64 + nt*32 + (lane&31)
//   k0  = kstep*64 + kc*16 + (lane>>5)*8   (B-frag: col=lane&31, k=(lane>>5)*8+j)
__global__ void prep_w2f(const float* __restrict__ W2, uint16_t* __restrict__ W2F) {
  const int e = blockIdx.x * 256 + threadIdx.x;  // 2048*256 = 524288 = 2^19
  const int lane = e & 63;
  const int nt = (e >> 6) & 1;
  const int wn2 = (e >> 7) & 1;
  const int kc = (e >> 8) & 3;
  const int kstep = (e >> 10) & 127;
  const int oh = (e >> 17) & 3;
  const int col = oh * 128 + wn2 * 64 + nt * 32 + (lane & 31);
  const int k0 = kstep * 64 + kc * 16 + (lane >> 5) * 8;
  uint16_t v[8];
#pragma unroll
  for (int j = 0; j < 8; ++j) v[j] = rne_bf16(W2[(size_t)(k0 + j) * ODIM + col]);
  *(u32x4*)(W2F + (size_t)e * 8) = *(u32x4*)v;
}

// ---- pre-kernel 2: b2sum[o] = sum_f b2[f][o] ----
__global__ void prep_small(const float* __restrict__ b2, float* __restrict__ b2sum) {
  const int t = blockIdx.x * 256 + threadIdx.x;  // 2*256 = 512
  float s = 0.f;
#pragma unroll
  for (int f = 0; f < FDIM; ++f) s += b2[(size_t)f * ODIM + t];
  b2sum[t] = s;
}

// ---- main kernel ----
// BM=256 x BN=128, split-K x2, O-quarters x4: grid 512 = 2 blocks/CU.
// B traffic = 512 blocks x 1MB = 536 MB (4x less than R1-R5's 2.1GB wall).
// B: fragment-linear global->VGPR, prefetched 1 step ahead. LDS: A only, 2x32KB
// double buffer, ONE barrier per step; genA(s+1) interleaves with mfma(s) in-wave.
// 4 waves as 2x2: wave (wm2,wn2) = rows wm2*128..+128, cols wn2*64..+64.
__global__ __launch_bounds__(256, 2) void mlp_gemm(
    const float* __restrict__ x, const float* __restrict__ W1,
    const float* __restrict__ b1, const uint16_t* __restrict__ W2F,
    const float* __restrict__ b2sum, float* __restrict__ out) {
  __shared__ __align__(16) uint16_t As[2][BM * BK];  // 2 x 32 KB

  const int tid = threadIdx.x;
  const int bid = blockIdx.x;
  const int oh = bid & 3;          // O-quarter; bid%8 -> XCD keeps (oh,kh) fixed/XCD
  const int kh = (bid >> 2) & 1;   // K-half
  const int m0 = (bid >> 3) * BM;

  const int wid = tid >> 6;
  const int lane = tid & 63;
  const int wm2 = wid >> 1;        // row-half of the wave (128 rows)
  const int wn2 = wid & 1;         // col-half (64 cols)
  const int l31 = lane & 31;
  const int l5 = lane >> 5;

  // wave-uniform fragment-linear B base (element units)
  const uint16_t* wfbase =
      W2F + (size_t)oh * 1048576 + (size_t)wn2 * 1024 + (size_t)lane * 8;

  f32x16 acc[4][2];
#pragma unroll
  for (int i = 0; i < 4; ++i)
#pragma unroll
    for (int j = 0; j < 2; ++j)
#pragma unroll
      for (int v = 0; v < 16; ++v) acc[i][j][v] = 0.f;

  auto loadB = [&](int s, bf16x8 (&rb)[8]) {
    const uint16_t* p = wfbase + (size_t)(kh * 64 + s) * 8192;
#pragma unroll
    for (int kc = 0; kc < 4; ++kc)
#pragma unroll
      for (int nt = 0; nt < 2; ++nt)
        rb[kc * 2 + nt] = *(const bf16x8*)(p + kc * 2048 + nt * 512);
  };

  // thread t generates row m0+t, all 64 k of this step (one f, one h-half)
  auto genA = [&](int s, int buf) {
    const int kstep = kh * 64 + s;
    const int f = kstep >> 1;
    const int h0 = (kstep & 1) * 64;
    const float xv = x[(size_t)(m0 + tid) * FDIM + f];
    const float* w1p = W1 + f * HDIM + h0;  // wave-uniform rows: L1 broadcast
    const float* b1p = b1 + f * HDIM + h0;
    uint16_t* arow = &As[buf][tid * BK];
#pragma unroll
    for (int g = 0; g < 8; ++g) {
      float wv[8], bv[8];
      *(f32x4v*)&wv[0] = *(const f32x4v*)(w1p + g * 8);
      *(f32x4v*)&wv[4] = *(const f32x4v*)(w1p + g * 8 + 4);
      *(f32x4v*)&bv[0] = *(const f32x4v*)(b1p + g * 8);
      *(f32x4v*)&bv[4] = *(const f32x4v*)(b1p + g * 8 + 4);
      u32x4 ov;
#pragma unroll
      for (int p = 0; p < 4; ++p) {
        float p0 = fmaf(xv, wv[2 * p], bv[2 * p]);
        float p1 = fmaf(xv, wv[2 * p + 1], bv[2 * p + 1]);
        // elu = max(pre,0) + min(exp(pre)-1, 0)   (branch-free, no cndmask)
        float r0 = fmaxf(p0, 0.f) + fminf(__expf(p0) - 1.f, 0.f);
        float r1 = fmaxf(p1, 0.f) + fminf(__expf(p1) - 1.f, 0.f);
        ov[p] = __builtin_amdgcn_perm(__builtin_bit_cast(uint32_t, r1),
                                      __builtin_bit_cast(uint32_t, r0),
                                      0x07060302u);
      }
      *(u32x4*)(arow + ((g ^ (tid & 7)) * 8)) = ov;  // XOR-swizzled 16B groups
    }
  };

  auto domfma = [&](int buf, bf16x8 (&rb)[8]) {
#pragma unroll
    for (int kc = 0; kc < 4; ++kc) {
      const int g = kc * 2 + l5;  // A-frag: row=lane&31, k=(lane>>5)*8+j
      bf16x8 af[4];
#pragma unroll
      for (int mt = 0; mt < 4; ++mt) {
        const int row = wm2 * 128 + mt * 32 + l31;
        af[mt] = *(const bf16x8*)&As[buf][row * BK + ((g ^ (row & 7)) * 8)];
      }
#pragma unroll
      for (int nt = 0; nt < 2; ++nt)
#pragma unroll
        for (int mt = 0; mt < 4; ++mt)
          acc[mt][nt] = __builtin_amdgcn_mfma_f32_32x32x16_bf16(
              af[mt], rb[kc * 2 + nt], acc[mt][nt], 0, 0, 0);
    }
  };

  bf16x8 rb0[8], rb1[8];
  loadB(0, rb0);
  genA(0, 0);

  for (int s = 0; s < NSTEPS; s += 2) {
    __syncthreads();                 // As[0](s) ready; As[1] free
    loadB(s + 1, rb1);               // B(s+1) in flight under this step
    genA(s + 1, 1);                  // VALU work, interleaves with mfma below
    domfma(0, rb0);
    __syncthreads();                 // As[1](s+1) ready; As[0] free
    if (s + 2 < NSTEPS) {
      loadB(s + 2, rb0);
      genA(s + 2, 0);
    }
    domfma(1, rb1);
  }

  // ---- epilogue: split-K atomic accumulate; kh=0 adds summed bias ----
  const int o0 = oh * 128 + wn2 * 64;
#pragma unroll
  for (int nt = 0; nt < 2; ++nt) {
    const int col = o0 + nt * 32 + l31;
    const float bias = (kh == 0) ? b2sum[col] * 0.125f : 0.f;
#pragma unroll
    for (int mt = 0; mt < 4; ++mt) {
      const int rbase = m0 + wm2 * 128 + mt * 32 + 4 * l5;
#pragma unroll
      for (int reg = 0; reg < 16; ++reg) {
        // 32x32 C/D: col=lane&31, row=(reg&3)+8*(reg>>2)+4*(lane>>5)
        const int row = rbase + (reg & 3) + 8 * (reg >> 2);
        unsafeAtomicAdd(&out[(size_t)row * ODIM + col],
                        acc[mt][nt][reg] * 0.125f + bias);
      }
    }
  }
}

extern "C" void kernel_launch(void* const* d_in, const int* in_sizes, int n_in,
                              void* d_out, int out_size, void* d_ws, size_t ws_size,
                              hipStream_t stream) {
  const float* x  = (const float*)d_in[0];
  const float* W1 = (const float*)d_in[1];
  const float* b1 = (const float*)d_in[2];
  const float* W2 = (const float*)d_in[3];
  const float* b2 = (const float*)d_in[4];
  float* out = (float*)d_out;

  char* ws = (char*)d_ws;
  float*    b2sum = (float*)ws;                 // 2KB
  uint16_t* W2F   = (uint16_t*)(ws + 4096);     // 8MB fragment-linear bf16

  hipMemsetAsync(out, 0, (size_t)NROWS * ODIM * sizeof(float), stream);
  prep_w2f<<<2048, 256, 0, stream>>>(W2, W2F);
  prep_small<<<2, 256, 0, stream>>>(b2, b2sum);
  // grid 512 = 64 m-blocks x 4 o-quarters x 2 k-halves = 2 blocks/CU
  mlp_gemm<<<512, 256, 0, stream>>>(x, W1, b1, W2F, b2sum, out);
}